// Round 20
// baseline (4495.234 us; speedup 1.0000x reference)
//
#include <hip/hip_runtime.h>

#define B_ 64
#define T_ 256
#define U_ 1024
#define G_ 4096   // 4*U
#define V_ 512
#define F_ 64
#define L_ 512

typedef __attribute__((ext_vector_type(4))) float f32x4;
typedef _Float16 f16;
typedef __attribute__((ext_vector_type(8))) f16 f16x8;
typedef unsigned long long u64;

__device__ __forceinline__ f16x8 ld8(const f16* p) {
  return *reinterpret_cast<const f16x8*>(p);
}
__device__ __forceinline__ float sigm(float x) { return 1.f / (1.f + __expf(-x)); }
__device__ __forceinline__ float tanh_f(float x) {
  float xc = fminf(fmaxf(x, -15.f), 15.f);
  float e = __expf(2.f * xc);
  return (e - 1.f) / (e + 1.f);
}

// ---------------- prep kernels ----------------

__global__ __launch_bounds__(256) void transpose_f16(const float* in, f16* out, int K, int N) {
  __shared__ float tile[64][65];
  long n0 = (long)blockIdx.x * 64, k0 = (long)blockIdx.y * 64;
  int c = threadIdx.x & 63, r4 = threadIdx.x >> 6;
#pragma unroll
  for (int rr = 0; rr < 16; ++rr) {
    int row = rr * 4 + r4;
    tile[row][c] = in[(k0 + row) * N + n0 + c];
  }
  __syncthreads();
#pragma unroll
  for (int rr = 0; rr < 16; ++rr) {
    int nrow = rr * 4 + r4;
    out[(n0 + nrow) * K + k0 + c] = (f16)tile[c][nrow];
  }
}

__global__ void conv_f16(const float* in, f16* out, int n) {
  int i = blockIdx.x * 256 + threadIdx.x;
  if (i < n) out[i] = (f16)in[i];
}

__global__ __launch_bounds__(256) void latA_kernel(const float* latent, const float* k1,
                                                   const float* b1, float* latA) {
  __shared__ float ls[8][512];
  int jc = blockIdx.x, bg = blockIdx.y;
  for (int i = threadIdx.x; i < 8 * 512; i += 256)
    ls[i >> 9][i & 511] = latent[(long)(bg * 8 + (i >> 9)) * L_ + (i & 511)];
  __syncthreads();
  int j = jc * 256 + threadIdx.x;
  float bv = b1[j];
  float acc[8];
#pragma unroll
  for (int i = 0; i < 8; ++i) acc[i] = bv;
  for (int k = 0; k < L_; ++k) {
    float w = k1[(long)k * G_ + j];
#pragma unroll
    for (int i = 0; i < 8; ++i) acc[i] += ls[i][k] * w;
  }
#pragma unroll
  for (int i = 0; i < 8; ++i) latA[(long)(bg * 8 + i) * G_ + j] = acc[i];
}

// ---------------- persistent dataflow scan ----------------

struct ScanP {
  const f16 *rk1T, *k2T, *rk2T, *k3T, *rk3T, *k1xT, *xf16;
  const float *latA, *b2, *b3;
  f16 *h1all, *h2all, *yall;   // h1all/h2all: [T][B][U]; yall: [B][T][U]
  unsigned *flg;               // counter per (layer,t,GROUP-of-8-chunks): [((l*T+t)*8+g)*16]
};

// 192 blocks x 512 threads (8 waves). block = (layer, uc). Wave w covers
// rotated K-window kbase=((w+uc)&7)*128, all 4 gates. Weights in registers.
// FINE-GRAINED dependencies: wave w only needs the 8 producer blocks of its
// K-window (group kbase>>7). Flags are per (layer,t,group) counters (reach 8).
// Each wave's lane0 polls its 2 group-flags with relaxed ATOMIC loads and the
// wave starts loading immediately — the 64-block straggle overlaps the load
// phase instead of preceding it. h stores sc1; h reads normal cached.
__global__ __launch_bounds__(512, 1) void scan_kernel(ScanP P) {
  int blk = blockIdx.x;
  int layer = blk >> 6;
  int uc = blk & 63;
  int tid = threadIdx.x;
  int w = tid >> 6, lane = tid & 63;
  int lrow = lane & 15, lk = lane >> 4;
  int u0 = uc * 16;
  int kbase = ((w + uc) & 7) * 128;   // rotated K-window
  int gidx = kbase >> 7;              // producer group for this window

  __shared__ float zp[8][64][68];

  // ---- weights into registers (once), for this wave's rotated K-window ----
  f16x8 wIn[4][4], wRec[4][4], wX[2][4];
  {
    const f16* Wr;
    const f16* Wi = nullptr;
    if (layer == 0)      { Wr = P.rk1T; }
    else if (layer == 1) { Wi = P.k2T;  Wr = P.rk2T; }
    else                 { Wi = P.k3T;  Wr = P.rk3T; }
#pragma unroll
    for (int kk = 0; kk < 4; ++kk)
#pragma unroll
      for (int g = 0; g < 4; ++g) {
        long row = (long)(g * 1024 + u0 + lrow);
        wRec[kk][g] = ld8(Wr + row * 1024 + kbase + kk * 32 + lk * 8);
        if (layer != 0)
          wIn[kk][g] = ld8(Wi + row * 1024 + kbase + kk * 32 + lk * 8);
      }
    if (layer == 0 && w == 0) {
#pragma unroll
      for (int kk = 0; kk < 2; ++kk)
#pragma unroll
        for (int g = 0; g < 4; ++g)
          wX[kk][g] = ld8(P.k1xT + (long)(g * 1024 + u0 + lrow) * F_ + kk * 32 + lk * 8);
    }
  }

  // ---- per-thread cell constants & state ----
  int cb = tid >> 3, cj = (tid & 7) * 2;  // batch row, unit offset (2 cells)
  float bz[4][2];
  if (layer == 0) {
    const float* lp = P.latA + (long)cb * G_ + u0 + cj;
#pragma unroll
    for (int i = 0; i < 2; ++i) {
      bz[0][i] = lp[i];        bz[1][i] = lp[1024 + i];
      bz[2][i] = lp[2048 + i]; bz[3][i] = lp[3072 + i];
    }
  } else {
    const float* bp = (layer == 1) ? P.b2 : P.b3;
#pragma unroll
    for (int i = 0; i < 2; ++i) {
      int u = u0 + cj + i;
      bz[0][i] = bp[u];        bz[1][i] = bp[1024 + u];
      bz[2][i] = bp[2048 + u]; bz[3][i] = bp[3072 + u];
    }
  }
  float creg[2] = {0.f, 0.f};

  // issue 4 pipelined 16B loads (one kk-batch, 4 m-tiles) — normal cached
  auto issue4 = [&](f16x8 (&d)[4], const f16* A, long astr, int k0) {
#pragma unroll
    for (int mt = 0; mt < 4; ++mt)
      asm volatile("global_load_dwordx4 %0, %1, off"
                   : "=v"(d[mt])
                   : "v"(A + (long)(mt * 16 + lrow) * astr + k0 + lk * 8));
  };

  for (int t = 0; t < T_; ++t) {
    // ---- per-WAVE dependency poll (lane 0), relaxed atomic group-flags ----
    {
      const unsigned* ga = (layer > 0)
          ? P.flg + ((size_t)((layer - 1) * T_ + t) * 8 + gidx) * 16 : nullptr;
      const unsigned* gb = (t > 0)
          ? P.flg + ((size_t)(layer * T_ + (t - 1)) * 8 + gidx) * 16 : nullptr;
      unsigned need = (ga ? 8u : 0u) + (gb ? 8u : 0u);
      if (lane == 0 && need) {
        while (true) {
          unsigned s = 0;
          if (ga) s += __hip_atomic_load(ga, __ATOMIC_RELAXED, __HIP_MEMORY_SCOPE_AGENT);
          if (gb) s += __hip_atomic_load(gb, __ATOMIC_RELAXED, __HIP_MEMORY_SCOPE_AGENT);
          if (s >= need) break;
          __builtin_amdgcn_s_sleep(1);
        }
      }
      __builtin_amdgcn_sched_barrier(0);  // keep loads below the poll
    }

    f32x4 acc[4][4] = {};

    // one matrix: 16 loads, counted-vmcnt batches of 4 (R11-proven)
    auto mmP = [&](const f16* A, long astr, f16x8 (&W)[4][4]) {
      f16x8 ab[4][4];
#pragma unroll
      for (int j = 0; j < 4; ++j) issue4(ab[j], A, astr, kbase + j * 32);
#pragma unroll
      for (int kk = 0; kk < 4; ++kk) {
        switch (kk) {
          case 0:  asm volatile("s_waitcnt vmcnt(12)"); break;
          case 1:  asm volatile("s_waitcnt vmcnt(8)");  break;
          case 2:  asm volatile("s_waitcnt vmcnt(4)");  break;
          default: asm volatile("s_waitcnt vmcnt(0)");  break;
        }
        __builtin_amdgcn_sched_barrier(0);
#pragma unroll
        for (int mt = 0; mt < 4; ++mt)
#pragma unroll
          for (int g = 0; g < 4; ++g)
            acc[mt][g] = __builtin_amdgcn_mfma_f32_16x16x32_f16(ab[kk][mt], W[kk][g], acc[mt][g], 0, 0, 0);
      }
    };

    if (layer == 0) {
      if (t > 0) mmP(P.h1all + (long)(t - 1) * (B_ * U_), U_, wRec);
      if (w == 0) {  // x-part: K=64, normal cached loads
#pragma unroll
        for (int kk = 0; kk < 2; ++kk) {
          int k0 = kk * 32;
          f16x8 a[4];
#pragma unroll
          for (int mt = 0; mt < 4; ++mt)
            a[mt] = ld8(P.xf16 + (long)(mt * 16 + lrow) * (T_ * F_) + t * F_ + k0 + lk * 8);
#pragma unroll
          for (int mt = 0; mt < 4; ++mt)
#pragma unroll
            for (int g = 0; g < 4; ++g)
              acc[mt][g] = __builtin_amdgcn_mfma_f32_16x16x32_f16(a[mt], wX[kk][g], acc[mt][g], 0, 0, 0);
        }
      }
    } else if (layer == 1) {
      mmP(P.h1all + (long)t * (B_ * U_), U_, wIn);
      if (t > 0) mmP(P.h2all + (long)(t - 1) * (B_ * U_), U_, wRec);
    } else {
      mmP(P.h2all + (long)t * (B_ * U_), U_, wIn);
      if (t > 0) mmP(P.yall + (long)(t - 1) * U_, (long)T_ * U_, wRec);
    }

    // partials: acc[mt][g][e] -> wave-plane w, gu = g*16+lrow, b = mt*16+lk*4+e
#pragma unroll
    for (int mt = 0; mt < 4; ++mt)
#pragma unroll
      for (int g = 0; g < 4; ++g)
        *reinterpret_cast<f32x4*>(&zp[w][g * 16 + lrow][mt * 16 + lk * 4]) = acc[mt][g];
    __syncthreads();

    // cell update: 2 (b,u) cells per thread, sum 8 wave-partials
    {
      float z[4][2];
#pragma unroll
      for (int g = 0; g < 4; ++g)
#pragma unroll
        for (int i = 0; i < 2; ++i) {
          int ul = g * 16 + cj + i;
          float s = 0.f;
#pragma unroll
          for (int p = 0; p < 8; ++p) s += zp[p][ul][cb];
          z[g][i] = s + bz[g][i];
        }
      unsigned short hpk[2];
#pragma unroll
      for (int i = 0; i < 2; ++i) {
        float gi = sigm(z[0][i]);
        float gf = sigm(z[1][i]);
        float gg = tanh_f(z[2][i]);
        float go = sigm(z[3][i]);
        float cn = gf * creg[i] + gi * gg;
        creg[i] = cn;
        f16 hv = (f16)(go * tanh_f(cn));
        hpk[i] = *reinterpret_cast<unsigned short*>(&hv);
      }
      unsigned packed = (unsigned)hpk[0] | ((unsigned)hpk[1] << 16);
      f16* hdst;
      if (layer == 0)      hdst = P.h1all + (long)t * (B_ * U_) + (long)cb * U_ + u0 + cj;
      else if (layer == 1) hdst = P.h2all + (long)t * (B_ * U_) + (long)cb * U_ + u0 + cj;
      else                 hdst = P.yall + (long)cb * (T_ * U_) + (long)t * U_ + u0 + cj;
      __hip_atomic_store((unsigned*)hdst, packed, __ATOMIC_RELAXED, __HIP_MEMORY_SCOPE_AGENT);
    }

    // ---- publish: barrier drains all waves' stores, then one group add ----
    __syncthreads();
    if (tid == 0)
      __hip_atomic_fetch_add(P.flg + ((size_t)(layer * T_ + t) * 8 + (uc >> 3)) * 16,
                             1u, __ATOMIC_RELAXED, __HIP_MEMORY_SCOPE_AGENT);
  }
}

// ---------------- projection + softmax ----------------

__global__ __launch_bounds__(256) void proj_kernel(const f16* yall, const f16* wT,
                                                   const float* bias, float* logits) {
  int wv = threadIdx.x >> 6, lane = threadIdx.x & 63;
  int lrow = lane & 15, lk = lane >> 4;
  long m0 = (long)blockIdx.y * 256 + wv * 64;
  int n0 = blockIdx.x * 64;
  f32x4 acc[4][4] = {};
  for (int k0 = 0; k0 < 1024; k0 += 32) {
    f16x8 a[4], b[4];
#pragma unroll
    for (int mt = 0; mt < 4; ++mt)
      a[mt] = ld8(yall + (m0 + mt * 16 + lrow) * U_ + k0 + lk * 8);
#pragma unroll
    for (int nt = 0; nt < 4; ++nt)
      b[nt] = ld8(wT + (long)(n0 + nt * 16 + lrow) * U_ + k0 + lk * 8);
#pragma unroll
    for (int mt = 0; mt < 4; ++mt)
#pragma unroll
      for (int nt = 0; nt < 4; ++nt)
        acc[mt][nt] = __builtin_amdgcn_mfma_f32_16x16x32_f16(a[mt], b[nt], acc[mt][nt], 0, 0, 0);
  }
#pragma unroll
  for (int mt = 0; mt < 4; ++mt)
#pragma unroll
    for (int nt = 0; nt < 4; ++nt)
#pragma unroll
      for (int e = 0; e < 4; ++e) {
        long row = m0 + mt * 16 + lk * 4 + e;
        int col = n0 + nt * 16 + lrow;
        logits[row * V_ + col] = acc[mt][nt][e] + bias[col];
      }
}

__global__ __launch_bounds__(256) void softmax_kernel(const float* logits, float* yout) {
  long row = (long)blockIdx.x * 4 + (threadIdx.x >> 6);
  int lane = threadIdx.x & 63;
  const float* lp = logits + row * V_;
  float vals[8];
#pragma unroll
  for (int j = 0; j < 8; ++j) vals[j] = lp[j * 64 + lane];
  float m = vals[0];
#pragma unroll
  for (int j = 1; j < 8; ++j) m = fmaxf(m, vals[j]);
  for (int off = 32; off > 0; off >>= 1) m = fmaxf(m, __shfl_xor(m, off));
  float sum = 0.f;
#pragma unroll
  for (int j = 0; j < 8; ++j) { vals[j] = __expf(vals[j] - m); sum += vals[j]; }
  for (int off = 32; off > 0; off >>= 1) sum += __shfl_xor(sum, off);
  float inv = 1.f / sum;
  float* yp = yout + row * V_;
#pragma unroll
  for (int j = 0; j < 8; ++j) yp[j * 64 + lane] = vals[j] * inv;
}

// ---------------- launch ----------------

extern "C" void kernel_launch(void* const* d_in, const int* in_sizes, int n_in,
                              void* d_out, int out_size, void* d_ws, size_t ws_size,
                              hipStream_t stream) {
  const float* latent = (const float*)d_in[0];
  const float* x      = (const float*)d_in[1];
  const float* k1     = (const float*)d_in[2];
  const float* rk1    = (const float*)d_in[3];
  const float* b1     = (const float*)d_in[4];
  const float* k2     = (const float*)d_in[5];
  const float* rk2    = (const float*)d_in[6];
  const float* b2     = (const float*)d_in[7];
  const float* k3     = (const float*)d_in[8];
  const float* rk3    = (const float*)d_in[9];
  const float* b3     = (const float*)d_in[10];
  const float* w      = (const float*)d_in[11];
  const float* bias   = (const float*)d_in[12];

  char* ws = (char*)d_ws;
  size_t o = 0;
  auto alloc = [&](size_t bytes) { size_t r = o; o += (bytes + 255) & ~(size_t)255; return r; };
  f16* rk1T = (f16*)(ws + alloc((size_t)G_ * U_ * 2));
  f16* k2T  = (f16*)(ws + alloc((size_t)G_ * U_ * 2));
  f16* rk2T = (f16*)(ws + alloc((size_t)G_ * U_ * 2));
  f16* k3T  = (f16*)(ws + alloc((size_t)G_ * U_ * 2));
  f16* rk3T = (f16*)(ws + alloc((size_t)G_ * U_ * 2));
  f16* k1xT = (f16*)(ws + alloc((size_t)G_ * F_ * 2));
  f16* wT   = (f16*)(ws + alloc((size_t)V_ * U_ * 2));
  f16* xf16 = (f16*)(ws + alloc((size_t)B_ * T_ * F_ * 2));
  float* latA = (float*)(ws + alloc((size_t)B_ * G_ * 4));
  f16* h1all = (f16*)(ws + alloc((size_t)T_ * B_ * U_ * 2));
  f16* h2all = (f16*)(ws + alloc((size_t)T_ * B_ * U_ * 2));
  f16* yall  = (f16*)(ws + alloc((size_t)B_ * T_ * U_ * 2));
  unsigned* flg = (unsigned*)(ws + alloc((size_t)3 * T_ * 8 * 16 * 4));

  hipMemsetAsync(flg, 0, (size_t)3 * T_ * 8 * 16 * 4, stream);

  dim3 blk256(256);
  transpose_f16<<<dim3(G_ / 64, U_ / 64), blk256, 0, stream>>>(rk1, rk1T, U_, G_);
  transpose_f16<<<dim3(G_ / 64, U_ / 64), blk256, 0, stream>>>(k2, k2T, U_, G_);
  transpose_f16<<<dim3(G_ / 64, U_ / 64), blk256, 0, stream>>>(rk2, rk2T, U_, G_);
  transpose_f16<<<dim3(G_ / 64, U_ / 64), blk256, 0, stream>>>(k3, k3T, U_, G_);
  transpose_f16<<<dim3(G_ / 64, U_ / 64), blk256, 0, stream>>>(rk3, rk3T, U_, G_);
  transpose_f16<<<dim3(G_ / 64, 1), blk256, 0, stream>>>(k1 + (size_t)L_ * G_, k1xT, F_, G_);
  transpose_f16<<<dim3(V_ / 64, U_ / 64), blk256, 0, stream>>>(w, wT, U_, V_);
  conv_f16<<<dim3((B_ * T_ * F_ + 255) / 256), blk256, 0, stream>>>(x, xf16, B_ * T_ * F_);
  latA_kernel<<<dim3(16, 8), blk256, 0, stream>>>(latent, k1, b1, latA);

  ScanP SP{rk1T, k2T, rk2T, k3T, rk3T, k1xT, xf16, latA, b2, b3, h1all, h2all, yall, flg};
  scan_kernel<<<dim3(192), dim3(512), 0, stream>>>(SP);

  float* logits = (float*)d_out + (size_t)B_ * T_ * V_;
  proj_kernel<<<dim3(V_ / 64, (B_ * T_) / 256), blk256, 0, stream>>>(yall, wT, bias, logits);
  softmax_kernel<<<dim3(B_ * T_ / 4), blk256, 0, stream>>>(logits, (float*)d_out);
}

// Round 21
// 3971.770 us; speedup vs baseline: 1.1318x; 1.1318x over previous
//
#include <hip/hip_runtime.h>

#define B_ 64
#define T_ 256
#define U_ 1024
#define G_ 4096   // 4*U
#define V_ 512
#define F_ 64
#define L_ 512

typedef __attribute__((ext_vector_type(4))) float f32x4;
typedef _Float16 f16;
typedef __attribute__((ext_vector_type(8))) f16 f16x8;
typedef unsigned long long u64;

__device__ __forceinline__ f16x8 ld8(const f16* p) {
  return *reinterpret_cast<const f16x8*>(p);
}
__device__ __forceinline__ float sigm(float x) { return 1.f / (1.f + __expf(-x)); }
__device__ __forceinline__ float tanh_f(float x) {
  float xc = fminf(fmaxf(x, -15.f), 15.f);
  float e = __expf(2.f * xc);
  return (e - 1.f) / (e + 1.f);
}

// ---------------- prep kernels ----------------

__global__ __launch_bounds__(256) void transpose_f16(const float* in, f16* out, int K, int N) {
  __shared__ float tile[64][65];
  long n0 = (long)blockIdx.x * 64, k0 = (long)blockIdx.y * 64;
  int c = threadIdx.x & 63, r4 = threadIdx.x >> 6;
#pragma unroll
  for (int rr = 0; rr < 16; ++rr) {
    int row = rr * 4 + r4;
    tile[row][c] = in[(k0 + row) * N + n0 + c];
  }
  __syncthreads();
#pragma unroll
  for (int rr = 0; rr < 16; ++rr) {
    int nrow = rr * 4 + r4;
    out[(n0 + nrow) * K + k0 + c] = (f16)tile[c][nrow];
  }
}

__global__ void conv_f16(const float* in, f16* out, int n) {
  int i = blockIdx.x * 256 + threadIdx.x;
  if (i < n) out[i] = (f16)in[i];
}

__global__ __launch_bounds__(256) void latA_kernel(const float* latent, const float* k1,
                                                   const float* b1, float* latA) {
  __shared__ float ls[8][512];
  int jc = blockIdx.x, bg = blockIdx.y;
  for (int i = threadIdx.x; i < 8 * 512; i += 256)
    ls[i >> 9][i & 511] = latent[(long)(bg * 8 + (i >> 9)) * L_ + (i & 511)];
  __syncthreads();
  int j = jc * 256 + threadIdx.x;
  float bv = b1[j];
  float acc[8];
#pragma unroll
  for (int i = 0; i < 8; ++i) acc[i] = bv;
  for (int k = 0; k < L_; ++k) {
    float w = k1[(long)k * G_ + j];
#pragma unroll
    for (int i = 0; i < 8; ++i) acc[i] += ls[i][k] * w;
  }
#pragma unroll
  for (int i = 0; i < 8; ++i) latA[(long)(bg * 8 + i) * G_ + j] = acc[i];
}

// ---------------- persistent dataflow scan ----------------

struct ScanP {
  const f16 *rk1T, *k2T, *rk2T, *k3T, *rk3T, *k1xT, *xf16;
  const float *latA, *b2, *b3;
  f16 *h1all, *h2all, *yall;   // h1all/h2all: [T][B][U]; yall: [B][T][U]
  unsigned *flg;               // [(layer*T + t)*8 + sub] * 16
};

// 192 blocks x 512 threads (8 waves). block = (layer, uc). Wave w = K-eighth
// (K=128), all 4 gates. Weights in registers (32 f16x8/wave). A-loads: inline
// asm global_load_dwordx4 sc0 sc1 (LLC-coherent, PIPELINED), counted vmcnt.
// Sync: write-once h + vmcnt-drain + relaxed sub-flag protocol.
// BEST MEASURED CONFIG (R11): 3.974 ms, absmax 7.8e-3. Nine subsequent
// structural probes (R12-R20: fused GEMMs, packed/plain-load polls, cached
// reads, 2-phase split, K-rotation, group deps) all landed 3.97-4.50 ms —
// the scan is at the sync-latency floor of cross-workgroup recurrence on
// this fabric (all pipes <8% busy; chain = LLC round-trip sequence).
__global__ __launch_bounds__(512, 1) void scan_kernel(ScanP P) {
  int blk = blockIdx.x;
  int layer = blk >> 6;
  int uc = blk & 63;
  int tid = threadIdx.x;
  int w = tid >> 6, lane = tid & 63;
  int lrow = lane & 15, lk = lane >> 4;
  int u0 = uc * 16;
  int kbase = w * 128;

  __shared__ float zp[8][64][68];

  // ---- weights into registers (once) ----
  f16x8 wIn[4][4], wRec[4][4], wX[2][4];
  {
    const f16* Wr;
    const f16* Wi = nullptr;
    if (layer == 0)      { Wr = P.rk1T; }
    else if (layer == 1) { Wi = P.k2T;  Wr = P.rk2T; }
    else                 { Wi = P.k3T;  Wr = P.rk3T; }
#pragma unroll
    for (int kk = 0; kk < 4; ++kk)
#pragma unroll
      for (int g = 0; g < 4; ++g) {
        long row = (long)(g * 1024 + u0 + lrow);
        wRec[kk][g] = ld8(Wr + row * 1024 + kbase + kk * 32 + lk * 8);
        if (layer != 0)
          wIn[kk][g] = ld8(Wi + row * 1024 + kbase + kk * 32 + lk * 8);
      }
    if (layer == 0 && w == 0) {
#pragma unroll
      for (int kk = 0; kk < 2; ++kk)
#pragma unroll
        for (int g = 0; g < 4; ++g)
          wX[kk][g] = ld8(P.k1xT + (long)(g * 1024 + u0 + lrow) * F_ + kk * 32 + lk * 8);
    }
  }

  // ---- per-thread cell constants & state ----
  int cb = tid >> 3, cj = (tid & 7) * 2;  // batch row, unit offset (2 cells)
  float bz[4][2];
  if (layer == 0) {
    const float* lp = P.latA + (long)cb * G_ + u0 + cj;
#pragma unroll
    for (int i = 0; i < 2; ++i) {
      bz[0][i] = lp[i];        bz[1][i] = lp[1024 + i];
      bz[2][i] = lp[2048 + i]; bz[3][i] = lp[3072 + i];
    }
  } else {
    const float* bp = (layer == 1) ? P.b2 : P.b3;
#pragma unroll
    for (int i = 0; i < 2; ++i) {
      int u = u0 + cj + i;
      bz[0][i] = bp[u];        bz[1][i] = bp[1024 + u];
      bz[2][i] = bp[2048 + u]; bz[3][i] = bp[3072 + u];
    }
  }
  float creg[2] = {0.f, 0.f};

  auto waitflag = [&](unsigned* base) {
    while (true) {
      unsigned sum = 0;
#pragma unroll
      for (int i = 0; i < 8; ++i)
        sum += __hip_atomic_load(base + i * 16, __ATOMIC_RELAXED, __HIP_MEMORY_SCOPE_AGENT);
      if (sum == 64u) break;
      __builtin_amdgcn_s_sleep(1);
    }
  };

  // issue 4 pipelined LLC-coherent 16B loads (one kk-batch, 4 m-tiles)
  auto issue4 = [&](f16x8 (&d)[4], const f16* A, long astr, int k0) {
#pragma unroll
    for (int mt = 0; mt < 4; ++mt)
      asm volatile("global_load_dwordx4 %0, %1, off sc0 sc1"
                   : "=v"(d[mt])
                   : "v"(A + (long)(mt * 16 + lrow) * astr + k0 + lk * 8));
  };

  for (int t = 0; t < T_; ++t) {
    if (tid == 0) {
      if (layer > 0) waitflag(P.flg + (size_t)((layer - 1) * T_ + t) * 8 * 16);
      if (t > 0)     waitflag(P.flg + (size_t)(layer * T_ + (t - 1)) * 8 * 16);
    }
    __syncthreads();

    f32x4 acc[4][4] = {};

    // one matrix: issue all 16 loads, counted-vmcnt batches of 4
    auto mmP = [&](const f16* A, long astr, f16x8 (&W)[4][4]) {
      f16x8 ab[4][4];
#pragma unroll
      for (int j = 0; j < 4; ++j) issue4(ab[j], A, astr, kbase + j * 32);
#pragma unroll
      for (int kk = 0; kk < 4; ++kk) {
        switch (kk) {
          case 0:  asm volatile("s_waitcnt vmcnt(12)"); break;
          case 1:  asm volatile("s_waitcnt vmcnt(8)");  break;
          case 2:  asm volatile("s_waitcnt vmcnt(4)");  break;
          default: asm volatile("s_waitcnt vmcnt(0)");  break;
        }
        __builtin_amdgcn_sched_barrier(0);
#pragma unroll
        for (int mt = 0; mt < 4; ++mt)
#pragma unroll
          for (int g = 0; g < 4; ++g)
            acc[mt][g] = __builtin_amdgcn_mfma_f32_16x16x32_f16(ab[kk][mt], W[kk][g], acc[mt][g], 0, 0, 0);
      }
    };

    if (layer == 0) {
      if (t > 0) mmP(P.h1all + (long)(t - 1) * (B_ * U_), U_, wRec);
      if (w == 0) {  // x-part: K=64, normal cached loads
#pragma unroll
        for (int kk = 0; kk < 2; ++kk) {
          int k0 = kk * 32;
          f16x8 a[4];
#pragma unroll
          for (int mt = 0; mt < 4; ++mt)
            a[mt] = ld8(P.xf16 + (long)(mt * 16 + lrow) * (T_ * F_) + t * F_ + k0 + lk * 8);
#pragma unroll
          for (int mt = 0; mt < 4; ++mt)
#pragma unroll
            for (int g = 0; g < 4; ++g)
              acc[mt][g] = __builtin_amdgcn_mfma_f32_16x16x32_f16(a[mt], wX[kk][g], acc[mt][g], 0, 0, 0);
        }
      }
    } else if (layer == 1) {
      mmP(P.h1all + (long)t * (B_ * U_), U_, wIn);
      if (t > 0) mmP(P.h2all + (long)(t - 1) * (B_ * U_), U_, wRec);
    } else {
      mmP(P.h2all + (long)t * (B_ * U_), U_, wIn);
      if (t > 0) mmP(P.yall + (long)(t - 1) * U_, (long)T_ * U_, wRec);
    }

    // partials: acc[mt][g][e] -> wave-plane w, gu = g*16+lrow, b = mt*16+lk*4+e
#pragma unroll
    for (int mt = 0; mt < 4; ++mt)
#pragma unroll
      for (int g = 0; g < 4; ++g)
        *reinterpret_cast<f32x4*>(&zp[w][g * 16 + lrow][mt * 16 + lk * 4]) = acc[mt][g];
    __syncthreads();

    // cell update: 2 (b,u) cells per thread, sum 8 wave-partials
    {
      float z[4][2];
#pragma unroll
      for (int g = 0; g < 4; ++g)
#pragma unroll
        for (int i = 0; i < 2; ++i) {
          int ul = g * 16 + cj + i;
          float s = 0.f;
#pragma unroll
          for (int p = 0; p < 8; ++p) s += zp[p][ul][cb];
          z[g][i] = s + bz[g][i];
        }
      unsigned short hpk[2];
#pragma unroll
      for (int i = 0; i < 2; ++i) {
        float gi = sigm(z[0][i]);
        float gf = sigm(z[1][i]);
        float gg = tanh_f(z[2][i]);
        float go = sigm(z[3][i]);
        float cn = gf * creg[i] + gi * gg;
        creg[i] = cn;
        f16 hv = (f16)(go * tanh_f(cn));
        hpk[i] = *reinterpret_cast<unsigned short*>(&hv);
      }
      unsigned packed = (unsigned)hpk[0] | ((unsigned)hpk[1] << 16);
      f16* hdst;
      if (layer == 0)      hdst = P.h1all + (long)t * (B_ * U_) + (long)cb * U_ + u0 + cj;
      else if (layer == 1) hdst = P.h2all + (long)t * (B_ * U_) + (long)cb * U_ + u0 + cj;
      else                 hdst = P.yall + (long)cb * (T_ * U_) + (long)t * U_ + u0 + cj;
      __hip_atomic_store((unsigned*)hdst, packed, __ATOMIC_RELAXED, __HIP_MEMORY_SCOPE_AGENT);
    }

    // ---- publish: __syncthreads drains all waves' vmcnt, then one add ----
    __syncthreads();
    if (tid == 0)
      __hip_atomic_fetch_add(P.flg + ((size_t)(layer * T_ + t) * 8 + (uc >> 3)) * 16,
                             1u, __ATOMIC_RELAXED, __HIP_MEMORY_SCOPE_AGENT);
  }
}

// ---------------- projection + softmax ----------------

__global__ __launch_bounds__(256) void proj_kernel(const f16* yall, const f16* wT,
                                                   const float* bias, float* logits) {
  int wv = threadIdx.x >> 6, lane = threadIdx.x & 63;
  int lrow = lane & 15, lk = lane >> 4;
  long m0 = (long)blockIdx.y * 256 + wv * 64;
  int n0 = blockIdx.x * 64;
  f32x4 acc[4][4] = {};
  for (int k0 = 0; k0 < 1024; k0 += 32) {
    f16x8 a[4], b[4];
#pragma unroll
    for (int mt = 0; mt < 4; ++mt)
      a[mt] = ld8(yall + (m0 + mt * 16 + lrow) * U_ + k0 + lk * 8);
#pragma unroll
    for (int nt = 0; nt < 4; ++nt)
      b[nt] = ld8(wT + (long)(n0 + nt * 16 + lrow) * U_ + k0 + lk * 8);
#pragma unroll
    for (int mt = 0; mt < 4; ++mt)
#pragma unroll
      for (int nt = 0; nt < 4; ++nt)
        acc[mt][nt] = __builtin_amdgcn_mfma_f32_16x16x32_f16(a[mt], b[nt], acc[mt][nt], 0, 0, 0);
  }
#pragma unroll
  for (int mt = 0; mt < 4; ++mt)
#pragma unroll
    for (int nt = 0; nt < 4; ++nt)
#pragma unroll
      for (int e = 0; e < 4; ++e) {
        long row = m0 + mt * 16 + lk * 4 + e;
        int col = n0 + nt * 16 + lrow;
        logits[row * V_ + col] = acc[mt][nt][e] + bias[col];
      }
}

__global__ __launch_bounds__(256) void softmax_kernel(const float* logits, float* yout) {
  long row = (long)blockIdx.x * 4 + (threadIdx.x >> 6);
  int lane = threadIdx.x & 63;
  const float* lp = logits + row * V_;
  float vals[8];
#pragma unroll
  for (int j = 0; j < 8; ++j) vals[j] = lp[j * 64 + lane];
  float m = vals[0];
#pragma unroll
  for (int j = 1; j < 8; ++j) m = fmaxf(m, vals[j]);
  for (int off = 32; off > 0; off >>= 1) m = fmaxf(m, __shfl_xor(m, off));
  float sum = 0.f;
#pragma unroll
  for (int j = 0; j < 8; ++j) { vals[j] = __expf(vals[j] - m); sum += vals[j]; }
  for (int off = 32; off > 0; off >>= 1) sum += __shfl_xor(sum, off);
  float inv = 1.f / sum;
  float* yp = yout + row * V_;
#pragma unroll
  for (int j = 0; j < 8; ++j) yp[j * 64 + lane] = vals[j] * inv;
}

// ---------------- launch ----------------

extern "C" void kernel_launch(void* const* d_in, const int* in_sizes, int n_in,
                              void* d_out, int out_size, void* d_ws, size_t ws_size,
                              hipStream_t stream) {
  const float* latent = (const float*)d_in[0];
  const float* x      = (const float*)d_in[1];
  const float* k1     = (const float*)d_in[2];
  const float* rk1    = (const float*)d_in[3];
  const float* b1     = (const float*)d_in[4];
  const float* k2     = (const float*)d_in[5];
  const float* rk2    = (const float*)d_in[6];
  const float* b2     = (const float*)d_in[7];
  const float* k3     = (const float*)d_in[8];
  const float* rk3    = (const float*)d_in[9];
  const float* b3     = (const float*)d_in[10];
  const float* w      = (const float*)d_in[11];
  const float* bias   = (const float*)d_in[12];

  char* ws = (char*)d_ws;
  size_t o = 0;
  auto alloc = [&](size_t bytes) { size_t r = o; o += (bytes + 255) & ~(size_t)255; return r; };
  f16* rk1T = (f16*)(ws + alloc((size_t)G_ * U_ * 2));
  f16* k2T  = (f16*)(ws + alloc((size_t)G_ * U_ * 2));
  f16* rk2T = (f16*)(ws + alloc((size_t)G_ * U_ * 2));
  f16* k3T  = (f16*)(ws + alloc((size_t)G_ * U_ * 2));
  f16* rk3T = (f16*)(ws + alloc((size_t)G_ * U_ * 2));
  f16* k1xT = (f16*)(ws + alloc((size_t)G_ * F_ * 2));
  f16* wT   = (f16*)(ws + alloc((size_t)V_ * U_ * 2));
  f16* xf16 = (f16*)(ws + alloc((size_t)B_ * T_ * F_ * 2));
  float* latA = (float*)(ws + alloc((size_t)B_ * G_ * 4));
  f16* h1all = (f16*)(ws + alloc((size_t)T_ * B_ * U_ * 2));
  f16* h2all = (f16*)(ws + alloc((size_t)T_ * B_ * U_ * 2));
  f16* yall  = (f16*)(ws + alloc((size_t)B_ * T_ * U_ * 2));
  unsigned* flg = (unsigned*)(ws + alloc((size_t)3 * T_ * 8 * 16 * 4));

  hipMemsetAsync(flg, 0, (size_t)3 * T_ * 8 * 16 * 4, stream);

  dim3 blk256(256);
  transpose_f16<<<dim3(G_ / 64, U_ / 64), blk256, 0, stream>>>(rk1, rk1T, U_, G_);
  transpose_f16<<<dim3(G_ / 64, U_ / 64), blk256, 0, stream>>>(k2, k2T, U_, G_);
  transpose_f16<<<dim3(G_ / 64, U_ / 64), blk256, 0, stream>>>(rk2, rk2T, U_, G_);
  transpose_f16<<<dim3(G_ / 64, U_ / 64), blk256, 0, stream>>>(k3, k3T, U_, G_);
  transpose_f16<<<dim3(G_ / 64, U_ / 64), blk256, 0, stream>>>(rk3, rk3T, U_, G_);
  transpose_f16<<<dim3(G_ / 64, 1), blk256, 0, stream>>>(k1 + (size_t)L_ * G_, k1xT, F_, G_);
  transpose_f16<<<dim3(V_ / 64, U_ / 64), blk256, 0, stream>>>(w, wT, U_, V_);
  conv_f16<<<dim3((B_ * T_ * F_ + 255) / 256), blk256, 0, stream>>>(x, xf16, B_ * T_ * F_);
  latA_kernel<<<dim3(16, 8), blk256, 0, stream>>>(latent, k1, b1, latA);

  ScanP SP{rk1T, k2T, rk2T, k3T, rk3T, k1xT, xf16, latA, b2, b3, h1all, h2all, yall, flg};
  scan_kernel<<<dim3(192), dim3(512), 0, stream>>>(SP);

  float* logits = (float*)d_out + (size_t)B_ * T_ * V_;
  proj_kernel<<<dim3(V_ / 64, (B_ * T_) / 256), blk256, 0, stream>>>(yall, wT, bias, logits);
  softmax_kernel<<<dim3(B_ * T_ / 4), blk256, 0, stream>>>(logits, (float*)d_out);
}